// Round 1
// baseline (172.552 us; speedup 1.0000x reference)
//
#include <hip/hip_runtime.h>

typedef __bf16 bf16x8 __attribute__((ext_vector_type(8)));
typedef float f32x4 __attribute__((ext_vector_type(4)));

#define HH 64
#define WW 64
#define HW 4096
#define COUT 256
#define NROWS 12      // staged input rows [rowbase, rowbase+11]
#define NCOLS 40      // staged input cols [colbase, colbase+39]
#define XROW 41       // px slots per staged row (+1 pad)
#define XS_OFF 18944  // byte offset of Xs inside smem (= 32*592 Bs bytes)
#define SMEM_SZ 34688 // 18944 + 2*12*41*16

// Raw barrier: flush LDS (lgkmcnt) but do NOT drain vmcnt — staging global
// loads stay in flight across the barrier (compiler waits at their uses).
__device__ __forceinline__ void bar_sync() {
    asm volatile("s_waitcnt lgkmcnt(0)" ::: "memory");
    __builtin_amdgcn_s_barrier();
    asm volatile("" ::: "memory");
}

// ---------------------------------------------------------------------------
// Kernel 1: blend circle weights -> bf16, pre-fragmented MFMA A layout.
// One block per output row o: coalesced float4 load of its 9216 B into LDS,
// then 288 fragments (cg,tap,q), each thread emitting all 9 taps' values for
// its 8-channel group. Replaces the 9216B-strided scatter reads (9x redundant)
// of the previous version.
// ---------------------------------------------------------------------------
__global__ __launch_bounds__(256) void prep_weights(const float* __restrict__ weight,
                                                    __bf16* __restrict__ wp) {
    __shared__ float ws[2304];
    const int o = blockIdx.x;
    const int tid = threadIdx.x;
    const float4* src = (const float4*)(weight + (size_t)o * 2304);
    float4* dst = (float4*)ws;
    #pragma unroll
    for (int i = 0; i < 3; ++i) {
        int idx = i * 256 + tid;
        if (idx < 576) dst[idx] = src[idx];
    }
    __syncthreads();
    const float Af = 0.70710678118654752f;
    const float Bf = 1.0f - Af;
    const int tm = o >> 4, rr = o & 15;
    for (int fid = tid; fid < 288; fid += 256) {
        const int cgtap = fid >> 2, q = fid & 3;
        const int cg = cgtap / 9, tap = cgtap - 9 * cg;
        const int c0 = cg * 32 + q * 8;
        bf16x8 v;
        #pragma unroll
        for (int j = 0; j < 8; ++j) {
            const float* w = ws + (c0 + j) * 9;
            float r;
            switch (tap) {
                case 0:  r = Af*(Af*w[0]+Bf*w[1]) + Bf*(Af*w[3]+Bf*w[4]); break;
                case 1:  r = w[1]; break;
                case 2:  r = Af*(Bf*w[1]+Af*w[2]) + Bf*(Bf*w[4]+Af*w[5]); break;
                case 3:  r = w[3]; break;
                case 4:  r = w[4]; break;
                case 5:  r = w[5]; break;
                case 6:  r = Bf*(Af*w[3]+Bf*w[4]) + Af*(Af*w[6]+Bf*w[7]); break;
                case 7:  r = w[7]; break;
                default: r = Bf*(Bf*w[4]+Af*w[5]) + Af*(Bf*w[7]+Af*w[8]); break;
            }
            v[j] = (__bf16)r;
        }
        *(bf16x8*)&wp[(size_t)(((cg * 9 + tap) * 16 + tm) * 64 + q * 16 + rr) << 3] = v;
    }
}

// ---------------------------------------------------------------------------
// Kernel 2: pipelined LDS-staged bilinear-sample + implicit GEMM.
// N-SPLIT for 2 blocks/CU: 512 blocks x 512 thr, tile M=256 x N=32.
// LDS 34.7KB (Bs 32x592 | Xs 2x12x41x16), acc[4][2] (32 AGPR).
// launch_bounds(512,4): 128 unified cap -> guarantees 2 blocks/CU so one
// block's MFMA phase overlaps the sibling block's gather/staging stalls
// (previous 1-block/CU version: all pipes <30% busy, barrier-serialized).
// Staging: 2 lane-contiguous slots/thread (waves 0-6; wave 7 stages 1 slot
// and owns the 2 extra gather units c=16,17). Col window [wb-6, wb+33]
// clamped; global fallback extended to cover col-window misses.
// ---------------------------------------------------------------------------
__global__ __launch_bounds__(512, 4) void dcn_main(
        const float* __restrict__ x, const float* __restrict__ off,
        const float* __restrict__ msk, const __bf16* __restrict__ wp,
        const float* __restrict__ bias, float* __restrict__ out) {
    __shared__ __align__(16) char smem[SMEM_SZ];  // Bs | Xs; epilogue: f32 scratch
    __bf16* Xs = (__bf16*)(smem + XS_OFF);
    char* BsB  = smem;
    const char* XsB = (const char*)smem + XS_OFF;

    const int tid  = threadIdx.x;
    const int wv   = tid >> 6;
    const int lane = tid & 63;
    const int q    = lane >> 4, rr = lane & 15;
    const int px   = lane & 31;            // sampling pixel column (local)
    const int side = lane >> 5;

    const int bid = blockIdx.x;
    const int xcd = bid & 7;
    const int p   = bid >> 3;              // 0..63 within XCD
    const int b   = xcd >> 1;
    const int h   = ((xcd & 1) << 5) | (p & 31);
    const int wb  = (p >> 5) << 5;         // 0 or 32 (siblings share XCD -> wp in L2)

    const int rowbase = min(max(h - 5, 0), HH - NROWS);
    const int colbase = min(max(wb - 6, 0), WW - NCOLS);
    const float* xb = x + (size_t)b * 256 * HW;

    // ---- staging slot geometry: 2 slots/thread, lane-contiguous -----------
    // 960 slots = 2 sg x 12 rows x 40 cols; k=1 valid for tid<448 (waves 0-6).
    int PXO[2], XA[2];
    #pragma unroll
    for (int k = 0; k < 2; ++k) {
        int slot = k * 512 + tid;
        if (slot < 960) {
            int sg  = slot / 480;
            int rem = slot - sg * 480;
            int row = rem / 40, col = rem - row * 40;
            PXO[k] = sg * 8 * HW + (rowbase + row) * 64 + (colbase + col);
            XA[k]  = ((sg * NROWS + row) * XROW + col) << 3;   // bf16 elem index
        }
    }
    const bool st1 = (tid < 448);

    // ---- per-thread gather-unit params, computed ONCE ---------------------
    // k=0: c = wv + 8*side (c 0..15, all waves). k=1 (wave 7 only): c = 16+side.
    const int nu = (wv == 7) ? 2 : 1;
    float W00[2], W01[2], W10[2], W11[2];
    int AY0[2], AY1[2], DXO[2], COLB[2], GP[2];
    #pragma unroll
    for (int k = 0; k < 2; ++k) {
        if (k < nu) {
            int c = (k == 0) ? (wv + 8 * side) : (16 + side);
            int sg = c / 9, tap = c - 9 * sg;
            int ki = tap / 3, kj = tap - 3 * ki;
            const float* offp = off + (size_t)b * 18 * HW + h * 64 + wb + px;
            float dy = offp[(2 * tap) * HW];
            float dx = offp[(2 * tap + 1) * HW];
            float mv = msk[(size_t)b * 9 * HW + (size_t)tap * HW + h * 64 + wb + px];
            float py  = (float)(h - 1 + ki) + dy;
            float pxf = (float)(wb + px - 1 + kj) + dx;
            float y0f = floorf(py), x0f = floorf(pxf);
            float ly = py - y0f, lx = pxf - x0f;
            float hy = 1.0f - ly, hx = 1.0f - lx;
            int y0 = (int)y0f, x0 = (int)x0f;
            int y1 = y0 + 1, x1 = x0 + 1;
            bool vy0 = (y0 >= 0) && (y0 < HH), vy1 = (y1 >= 0) && (y1 < HH);
            bool vx0 = (x0 >= 0) && (x0 < WW), vx1 = (x1 >= 0) && (x1 < WW);
            int cy0 = min(max(y0, 0), HH - 1), cy1 = min(max(y1, 0), HH - 1);
            int cx0 = min(max(x0, 0), WW - 1), cx1 = min(max(x1, 0), WW - 1);
            W00[k] = (vy0 && vx0) ? hy * hx * mv : 0.0f;
            W01[k] = (vy0 && vx1) ? hy * lx * mv : 0.0f;
            W10[k] = (vy1 && vx0) ? ly * hx * mv : 0.0f;
            W11[k] = (vy1 && vx1) ? ly * lx * mv : 0.0f;
            int ry0 = min(max(cy0 - rowbase, 0), NROWS - 1);
            int ry1 = min(max(cy1 - rowbase, 0), NROWS - 1);
            int rx0 = min(max(cx0 - colbase, 0), NCOLS - 1);
            int rx1 = min(max(cx1 - colbase, 0), NCOLS - 1);
            bool in_r0 = (cy0 >= rowbase) && (cy0 < rowbase + NROWS);
            bool in_r1 = (cy1 >= rowbase) && (cy1 < rowbase + NROWS);
            bool in_c0 = (cx0 >= colbase) && (cx0 < colbase + NCOLS);
            bool in_c1 = (cx1 >= colbase) && (cx1 < colbase + NCOLS);
            bool useG = (vy0 && vx0 && !(in_r0 && in_c0))
                     || (vy0 && vx1 && !(in_r0 && in_c1))
                     || (vy1 && vx0 && !(in_r1 && in_c0))
                     || (vy1 && vx1 && !(in_r1 && in_c1));
            AY0[k]  = ((sg * NROWS + ry0) * XROW + rx0) * 16;
            AY1[k]  = ((sg * NROWS + ry1) * XROW + rx0) * 16;
            DXO[k]  = (rx1 - rx0) * 16;
            COLB[k] = (tap * 32 + sg * 8) * 2;
            GP[k]   = cy0 | (cy1 << 6) | (cx0 << 12) | (cx1 << 18) | (sg << 24)
                    | (useG ? (1u << 31) : 0);
        }
    }

    f32x4 acc[4][2];
    #pragma unroll
    for (int i = 0; i < 4; ++i)
        #pragma unroll
        for (int n = 0; n < 2; ++n)
            acc[i][n] = (f32x4)0.0f;

    const int tm0   = (wv & 3) * 4;
    const int klbeg = (wv & 4) ? 5 : 0;
    const int nkl   = (wv & 4) ? 4 : 5;

    // ---- preload stage 0 staging values into regs -------------------------
    float R[2][8];
    #pragma unroll
    for (int k = 0; k < 2; ++k) {
        if (k == 0 || st1) {
            const float* pp = xb + PXO[k];
            #pragma unroll
            for (int j = 0; j < 8; ++j) R[k][j] = pp[j * HW];
        }
    }

    #pragma unroll 1
    for (int s = 0; s < 16; ++s) {
        const int cg = s >> 1, half = s & 1;
        bar_sync();   // Xs(s-1) gathers done; Bs(cg-1) MFMA reads done
        // ---- write Xs from regs (2 lane-contiguous b128, conflict-free) ---
        #pragma unroll
        for (int k = 0; k < 2; ++k) {
            if (k == 0 || st1) {
                bf16x8 v;
                #pragma unroll
                for (int j = 0; j < 8; ++j) v[j] = (__bf16)R[k][j];
                *(bf16x8*)&Xs[XA[k]] = v;
            }
        }
        // ---- issue next stage's global loads (stay in flight) -------------
        if (s < 15) {
            const int s1 = s + 1;
            const int cbase = (s1 >> 1) * 32 + (s1 & 1) * 16;
            #pragma unroll
            for (int k = 0; k < 2; ++k) {
                if (k == 0 || st1) {
                    const float* pp = xb + (size_t)cbase * HW + PXO[k];
                    #pragma unroll
                    for (int j = 0; j < 8; ++j) R[k][j] = pp[j * HW];
                }
            }
        }
        bar_sync();   // Xs ready
        // ---- gather: 1 unit/thread (wave 7: 2 units) ----------------------
        #pragma unroll
        for (int k = 0; k < 2; ++k) {
            if (k < nu) {
                bf16x8 c00 = *(const bf16x8*)(XsB + AY0[k]);
                bf16x8 c01 = *(const bf16x8*)(XsB + AY0[k] + DXO[k]);
                bf16x8 c10 = *(const bf16x8*)(XsB + AY1[k]);
                bf16x8 c11 = *(const bf16x8*)(XsB + AY1[k] + DXO[k]);
                float w0 = W00[k], w1 = W01[k], w2 = W10[k], w3 = W11[k];
                bf16x8 res;
                #pragma unroll
                for (int j = 0; j < 8; ++j) {
                    float v = w0 * (float)c00[j] + w1 * (float)c01[j]
                            + w2 * (float)c10[j] + w3 * (float)c11[j];
                    res[j] = (__bf16)v;
                }
                int gp = GP[k];
                if (gp < 0) {   // rare: valid corner outside staged window
                    int cy0 = gp & 63, cy1 = (gp >> 6) & 63;
                    int cx0 = (gp >> 12) & 63, cx1 = (gp >> 18) & 63;
                    int sg = (gp >> 24) & 3;
                    const float* xc = xb + (size_t)(cg * 32 + half * 16 + sg * 8) * HW;
                    int i00 = cy0 * 64 + cx0, i01 = cy0 * 64 + cx1;
                    int i10 = cy1 * 64 + cx0, i11 = cy1 * 64 + cx1;
                    #pragma unroll
                    for (int j = 0; j < 8; ++j) {
                        float v = w0 * xc[i00] + w1 * xc[i01]
                                + w2 * xc[i10] + w3 * xc[i11];
                        res[j] = (__bf16)v;
                        xc += HW;
                    }
                }
                *(bf16x8*)(BsB + px * 592 + COLB[k] + half * 32) = res;
            }
        }
        if (half) {
            bar_sync();   // Bs complete (both halves)
            // ---- MFMA: M=64/wave, 2 n-tiles, kl split across wave halves --
            const __bf16* ap = wp + ((size_t)((cg * 9 + klbeg) * 16 + tm0) * 64 + lane) * 8;
            bf16x8 a0 = *(const bf16x8*)ap;
            bf16x8 a1 = *(const bf16x8*)(ap + 512);
            bf16x8 a2 = *(const bf16x8*)(ap + 1024);
            bf16x8 a3 = *(const bf16x8*)(ap + 1536);
            int kc = (klbeg * 32 + q * 8) * 2;   // byte col in Bs row
            #pragma unroll 1
            for (int t = 0; t < nkl; ++t) {
                bf16x8 n0 = a0, n1 = a1, n2 = a2, n3 = a3;
                if (t + 1 < nkl) {
                    const __bf16* np = ap + 8192;
                    n0 = *(const bf16x8*)np;
                    n1 = *(const bf16x8*)(np + 512);
                    n2 = *(const bf16x8*)(np + 1024);
                    n3 = *(const bf16x8*)(np + 1536);
                }
                const char* bp = BsB + rr * 592 + kc;
                bf16x8 bb0 = *(const bf16x8*)(bp);
                bf16x8 bb1 = *(const bf16x8*)(bp + 16 * 592);
                acc[0][0] = __builtin_amdgcn_mfma_f32_16x16x32_bf16(a0, bb0, acc[0][0], 0, 0, 0);
                acc[1][0] = __builtin_amdgcn_mfma_f32_16x16x32_bf16(a1, bb0, acc[1][0], 0, 0, 0);
                acc[2][0] = __builtin_amdgcn_mfma_f32_16x16x32_bf16(a2, bb0, acc[2][0], 0, 0, 0);
                acc[3][0] = __builtin_amdgcn_mfma_f32_16x16x32_bf16(a3, bb0, acc[3][0], 0, 0, 0);
                acc[0][1] = __builtin_amdgcn_mfma_f32_16x16x32_bf16(a0, bb1, acc[0][1], 0, 0, 0);
                acc[1][1] = __builtin_amdgcn_mfma_f32_16x16x32_bf16(a1, bb1, acc[1][1], 0, 0, 0);
                acc[2][1] = __builtin_amdgcn_mfma_f32_16x16x32_bf16(a2, bb1, acc[2][1], 0, 0, 0);
                acc[3][1] = __builtin_amdgcn_mfma_f32_16x16x32_bf16(a3, bb1, acc[3][1], 0, 0, 0);
                ap += 8192;
                kc += 64;
                a0 = n0; a1 = n1; a2 = n2; a3 = n3;
            }
        }
    }

    // ---- epilogue: cross-wave kl-partial reduce via LDS, then store -------
    float* scr = (float*)smem;   // Bs/Xs dead now; 4 waves x 2048 f32 = 32KB
    bar_sync();
    if (wv >= 4) {
        const int base = (wv - 4) * 2048 + lane * 4;
        #pragma unroll
        for (int i = 0; i < 4; ++i)
            #pragma unroll
            for (int n = 0; n < 2; ++n)
                *(f32x4*)&scr[base + (i * 2 + n) * 256] = acc[i][n];
    }
    bar_sync();
    if (wv < 4) {
        const int mrow = wv * 64;
        const int base = wv * 2048 + lane * 4;
        #pragma unroll
        for (int i = 0; i < 4; ++i) {
            #pragma unroll
            for (int n = 0; n < 2; ++n) {
                f32x4 pv = *(const f32x4*)&scr[base + (i * 2 + n) * 256];
                #pragma unroll
                for (int e = 0; e < 4; ++e) {
                    int m = mrow + i * 16 + q * 4 + e;
                    out[((size_t)b * COUT + m) * HW + h * 64 + wb + n * 16 + rr]
                        = acc[i][n][e] + pv[e] + bias[m];
                }
            }
        }
    }
}

extern "C" void kernel_launch(void* const* d_in, const int* in_sizes, int n_in,
                              void* d_out, int out_size, void* d_ws, size_t ws_size,
                              hipStream_t stream) {
    const float* x      = (const float*)d_in[0];   // [4,256,64,64]
    const float* off    = (const float*)d_in[1];   // [4,18,64,64]
    const float* msk    = (const float*)d_in[2];   // [4,9,64,64]
    const float* weight = (const float*)d_in[3];   // [256,256,3,3]
    const float* bias   = (const float*)d_in[4];   // [256]
    float* out = (float*)d_out;                    // [4,256,64,64]

    __bf16* wp = (__bf16*)d_ws;                    // 589824 bf16 = 1.18 MB

    prep_weights<<<256, 256, 0, stream>>>(weight, wp);
    dcn_main<<<512, 512, 0, stream>>>(x, off, msk, wp, bias, out);
}

// Round 2
// 162.581 us; speedup vs baseline: 1.0613x; 1.0613x over previous
//
#include <hip/hip_runtime.h>

typedef __bf16 bf16x8 __attribute__((ext_vector_type(8)));
typedef float f32x4 __attribute__((ext_vector_type(4)));

#define HH 64
#define WW 64
#define HW 4096
#define COUT 256
#define NROWS 12       // staged input rows [rowbase, rowbase+11]
#define NCOLS 40       // staged input cols [colbase, colbase+39]
#define BS_SZ 18944    // Bs: 32 px-rows x 592 B
#define XS_OFF 18944
#define XS_HALF 15360  // per ch-half: 960 slots x 16 B (f32x4)
#define SMEM_SZ 49664  // Bs + 2 ch-halves of Xs

// lgkm-only barrier: staging global loads stay in flight across it.
__device__ __forceinline__ void bar_sync() {
    asm volatile("s_waitcnt lgkmcnt(0)" ::: "memory");
    __builtin_amdgcn_s_barrier();
    asm volatile("" ::: "memory");
}
// full barrier: additionally drains this wave's DMA (global_load_lds) issues.
__device__ __forceinline__ void bar_sync_vm() {
    asm volatile("s_waitcnt vmcnt(0) lgkmcnt(0)" ::: "memory");
    __builtin_amdgcn_s_barrier();
    asm volatile("" ::: "memory");
}

// ---------------------------------------------------------------------------
// Kernel 1: blend circle weights -> bf16, pre-fragmented MFMA A layout.
// One block per output row o: coalesced float4 load into LDS, then fragments.
// ---------------------------------------------------------------------------
__global__ __launch_bounds__(256) void prep_weights(const float* __restrict__ weight,
                                                    __bf16* __restrict__ wp) {
    __shared__ float ws[2304];
    const int o = blockIdx.x;
    const int tid = threadIdx.x;
    const float4* src = (const float4*)(weight + (size_t)o * 2304);
    float4* dst = (float4*)ws;
    #pragma unroll
    for (int i = 0; i < 3; ++i) {
        int idx = i * 256 + tid;
        if (idx < 576) dst[idx] = src[idx];
    }
    __syncthreads();
    const float Af = 0.70710678118654752f;
    const float Bf = 1.0f - Af;
    const int tm = o >> 4, rr = o & 15;
    for (int fid = tid; fid < 288; fid += 256) {
        const int cgtap = fid >> 2, q = fid & 3;
        const int cg = cgtap / 9, tap = cgtap - 9 * cg;
        const int c0 = cg * 32 + q * 8;
        bf16x8 v;
        #pragma unroll
        for (int j = 0; j < 8; ++j) {
            const float* w = ws + (c0 + j) * 9;
            float r;
            switch (tap) {
                case 0:  r = Af*(Af*w[0]+Bf*w[1]) + Bf*(Af*w[3]+Bf*w[4]); break;
                case 1:  r = w[1]; break;
                case 2:  r = Af*(Bf*w[1]+Af*w[2]) + Bf*(Bf*w[4]+Af*w[5]); break;
                case 3:  r = w[3]; break;
                case 4:  r = w[4]; break;
                case 5:  r = w[5]; break;
                case 6:  r = Bf*(Af*w[3]+Bf*w[4]) + Af*(Af*w[6]+Bf*w[7]); break;
                case 7:  r = w[7]; break;
                default: r = Bf*(Bf*w[4]+Af*w[5]) + Af*(Bf*w[7]+Af*w[8]); break;
            }
            v[j] = (__bf16)r;
        }
        *(bf16x8*)&wp[(size_t)(((cg * 9 + tap) * 16 + tm) * 64 + q * 16 + rr) << 3] = v;
    }
}

// ---------------------------------------------------------------------------
// Kernel 2: DMA-staged (global_load_lds, f32 Xs) bilinear-sample + implicit
// GEMM. 512 blocks x 256 thr (4 waves = 1 wave/SIMD). Tile M=256 x N=32.
// launch_bounds(256,2): 2 blocks/CU co-resident at a comfortable 256-reg cap
// (R1 lesson: 512-thr blocks need <=128 regs for 2/CU -> spill disaster).
// Staging: 30 global_load_lds(width=4)/wave/stage, zero VALU, 5 offset regs
// (period-5 row structure). Xs split in ch-halves -> linear DMA dest AND
// conflict-free stride-16B gather b128 reads. f32 corners halve gather VALU
// (no bf16->f32 cvt). Full-K per wave -> direct-store epilogue (no reduce).
// ---------------------------------------------------------------------------
__global__ __launch_bounds__(256, 2) void dcn_main(
        const float* __restrict__ x, const float* __restrict__ off,
        const float* __restrict__ msk, const __bf16* __restrict__ wp,
        const float* __restrict__ bias, float* __restrict__ out) {
    __shared__ __align__(16) char smem[SMEM_SZ];
    char* BsB = smem;
    const char* X0 = (const char*)smem + XS_OFF;       // ch 0..3 of each sg-slot
    const char* X1 = X0 + XS_HALF;                     // ch 4..7

    const int tid  = threadIdx.x;
    const int wv   = tid >> 6;             // 0..3
    const int lane = tid & 63;
    const int q    = lane >> 4, rr = lane & 15;
    const int px   = tid & 31;             // sampling pixel column (local)

    const int bid = blockIdx.x;
    const int xcd = bid & 7;
    const int p   = bid >> 3;
    const int b   = xcd >> 1;
    const int h   = ((xcd & 1) << 5) | (p & 31);
    const int wb  = (p >> 5) << 5;         // 0 or 32

    const int rowbase = min(max(h - 5, 0), HH - NROWS);
    const int colbase = min(max(wb - 6, 0), WW - NCOLS);
    const float* xb = x + (size_t)b * 256 * HW;

    // ---- DMA offsets: wave wv covers e' = wv*1920 + j*64 + lane -----------
    // half = wv>>1 (ch 0-3 vs 4-7), sg = wv&1, slot-in-sg = j*16 + (lane>>2),
    // ch-low = lane&3. Rows of 40 cols, 16 slots/inst -> period 5 insts = 2
    // rows -> OFF[j] = OFF[j%5] + (j/5)*512 bytes.
    int OFF[5];
    {
        const int chrel = ((wv & 1) << 3) + ((wv >> 1) << 2) + (lane & 3);
        #pragma unroll
        for (int bq = 0; bq < 5; ++bq) {
            int sp = bq * 16 + (lane >> 2);
            int rw = sp / 40, cl = sp - rw * 40;
            OFF[bq] = (chrel * HW + (rowbase + rw) * 64 + colbase + cl) * 4;
        }
    }
    char* ldsb = (char*)smem + XS_OFF + wv * 7680;

    // ---- per-thread gather-unit params, computed ONCE ---------------------
    // unit k: k=0 -> c = tid>>5 (0..7); k=1 -> c = 8+(tid>>5); k=2 (wave 0
    // only, tid<64) -> c = 16+(tid>>5) in {16,17}. px identical for all k.
    const int nu = (wv == 0) ? 3 : 2;
    float W00[3], W01[3], W10[3], W11[3];
    int AY0[3], AY1[3], DXO[3], COLB[3], GP[3];
    #pragma unroll
    for (int k = 0; k < 3; ++k) {
        if (k < nu) {
            int c = (k == 0) ? (tid >> 5) : ((k == 1) ? 8 + (tid >> 5) : 16 + (tid >> 5));
            int sg = c / 9, tap = c - 9 * sg;
            int ki = tap / 3, kj = tap - 3 * ki;
            const float* offp = off + (size_t)b * 18 * HW + h * 64 + wb + px;
            float dy = offp[(2 * tap) * HW];
            float dx = offp[(2 * tap + 1) * HW];
            float mv = msk[(size_t)b * 9 * HW + (size_t)tap * HW + h * 64 + wb + px];
            float py  = (float)(h - 1 + ki) + dy;
            float pxf = (float)(wb + px - 1 + kj) + dx;
            float y0f = floorf(py), x0f = floorf(pxf);
            float ly = py - y0f, lx = pxf - x0f;
            float hy = 1.0f - ly, hx = 1.0f - lx;
            int y0 = (int)y0f, x0 = (int)x0f;
            int y1 = y0 + 1, x1 = x0 + 1;
            bool vy0 = (y0 >= 0) && (y0 < HH), vy1 = (y1 >= 0) && (y1 < HH);
            bool vx0 = (x0 >= 0) && (x0 < WW), vx1 = (x1 >= 0) && (x1 < WW);
            int cy0 = min(max(y0, 0), HH - 1), cy1 = min(max(y1, 0), HH - 1);
            int cx0 = min(max(x0, 0), WW - 1), cx1 = min(max(x1, 0), WW - 1);
            W00[k] = (vy0 && vx0) ? hy * hx * mv : 0.0f;
            W01[k] = (vy0 && vx1) ? hy * lx * mv : 0.0f;
            W10[k] = (vy1 && vx0) ? ly * hx * mv : 0.0f;
            W11[k] = (vy1 && vx1) ? ly * lx * mv : 0.0f;
            int ry0 = min(max(cy0 - rowbase, 0), NROWS - 1);
            int ry1 = min(max(cy1 - rowbase, 0), NROWS - 1);
            int rx0 = min(max(cx0 - colbase, 0), NCOLS - 1);
            int rx1 = min(max(cx1 - colbase, 0), NCOLS - 1);
            bool in_r0 = (cy0 >= rowbase) && (cy0 < rowbase + NROWS);
            bool in_r1 = (cy1 >= rowbase) && (cy1 < rowbase + NROWS);
            bool in_c0 = (cx0 >= colbase) && (cx0 < colbase + NCOLS);
            bool in_c1 = (cx1 >= colbase) && (cx1 < colbase + NCOLS);
            bool useG = (vy0 && vx0 && !(in_r0 && in_c0))
                     || (vy0 && vx1 && !(in_r0 && in_c1))
                     || (vy1 && vx0 && !(in_r1 && in_c0))
                     || (vy1 && vx1 && !(in_r1 && in_c1));
            AY0[k]  = (sg * 480 + ry0 * 40 + rx0) * 16;
            AY1[k]  = (sg * 480 + ry1 * 40 + rx0) * 16;
            DXO[k]  = (rx1 - rx0) * 16;
            COLB[k] = (tap * 32 + sg * 8) * 2;
            GP[k]   = cy0 | (cy1 << 6) | (cx0 << 12) | (cx1 << 18) | (sg << 24)
                    | (useG ? (1u << 31) : 0);
        }
    }

    f32x4 acc[4][2];
    #pragma unroll
    for (int i = 0; i < 4; ++i)
        #pragma unroll
        for (int n = 0; n < 2; ++n)
            acc[i][n] = (f32x4)0.0f;

    const int tm0 = wv * 4;

    // ---- prologue: DMA stage-0 channels (cbase = 0) -----------------------
    {
        const char* gp0 = (const char*)xb;
        #pragma unroll
        for (int j = 0; j < 30; ++j)
            __builtin_amdgcn_global_load_lds(
                (const __attribute__((address_space(1))) void*)(gp0 + OFF[j % 5] + (j / 5) * 512),
                (__attribute__((address_space(3))) void*)(ldsb + j * 256), 4, 0, 0);
    }

    #pragma unroll 1
    for (int s = 0; s < 16; ++s) {
        const int cg = s >> 1, half = s & 1;
        bar_sync_vm();   // Xs(s) DMA drained block-wide; prev MFMA/Bs reads done
        // ---- gather: f32 corners from split Xs, blend, write Bs -----------
        #pragma unroll
        for (int k = 0; k < 3; ++k) {
            if (k < nu) {
                f32x4 a00 = *(const f32x4*)(X0 + AY0[k]);
                f32x4 a01 = *(const f32x4*)(X0 + AY0[k] + DXO[k]);
                f32x4 a10 = *(const f32x4*)(X0 + AY1[k]);
                f32x4 a11 = *(const f32x4*)(X0 + AY1[k] + DXO[k]);
                f32x4 b00 = *(const f32x4*)(X1 + AY0[k]);
                f32x4 b01 = *(const f32x4*)(X1 + AY0[k] + DXO[k]);
                f32x4 b10 = *(const f32x4*)(X1 + AY1[k]);
                f32x4 b11 = *(const f32x4*)(X1 + AY1[k] + DXO[k]);
                float w0 = W00[k], w1 = W01[k], w2 = W10[k], w3 = W11[k];
                bf16x8 res;
                #pragma unroll
                for (int jj = 0; jj < 4; ++jj) {
                    float v = w0 * a00[jj] + w1 * a01[jj] + w2 * a10[jj] + w3 * a11[jj];
                    res[jj] = (__bf16)v;
                }
                #pragma unroll
                for (int jj = 0; jj < 4; ++jj) {
                    float v = w0 * b00[jj] + w1 * b01[jj] + w2 * b10[jj] + w3 * b11[jj];
                    res[4 + jj] = (__bf16)v;
                }
                int gp = GP[k];
                if (gp < 0) {   // rare: valid corner outside staged window
                    int cy0 = gp & 63, cy1 = (gp >> 6) & 63;
                    int cx0 = (gp >> 12) & 63, cx1 = (gp >> 18) & 63;
                    int sg = (gp >> 24) & 3;
                    const float* xc = xb + (size_t)(cg * 32 + half * 16 + sg * 8) * HW;
                    int i00 = cy0 * 64 + cx0, i01 = cy0 * 64 + cx1;
                    int i10 = cy1 * 64 + cx0, i11 = cy1 * 64 + cx1;
                    #pragma unroll
                    for (int j = 0; j < 8; ++j) {
                        float v = w0 * xc[i00] + w1 * xc[i01]
                                + w2 * xc[i10] + w3 * xc[i11];
                        res[j] = (__bf16)v;
                        xc += HW;
                    }
                }
                *(bf16x8*)(BsB + px * 592 + COLB[k] + half * 32) = res;
            }
        }
        bar_sync();   // Xs reads + Bs(half) writes done block-wide
        // ---- issue next stage's DMA (flies across MFMA + next barrier) ----
        if (s < 15) {
            const int s1 = s + 1;
            const int cbase = (s1 >> 1) * 32 + (s1 & 1) * 16;
            const char* gp1 = (const char*)(xb + (size_t)cbase * HW);
            #pragma unroll
            for (int j = 0; j < 30; ++j)
                __builtin_amdgcn_global_load_lds(
                    (const __attribute__((address_space(1))) void*)(gp1 + OFF[j % 5] + (j / 5) * 512),
                    (__attribute__((address_space(3))) void*)(ldsb + j * 256), 4, 0, 0);
        }
        if (half) {
            // ---- MFMA: M=64/wave, 2 n-tiles, full kl 0..8 unrolled --------
            const __bf16* ap = wp + (size_t)(((cg * 9) * 16 + tm0) * 64 + lane) * 8;
            const char* bp = BsB + rr * 592 + q * 16;
            #pragma unroll
            for (int kl = 0; kl < 9; ++kl) {
                bf16x8 a0 = *(const bf16x8*)(ap + kl * 8192);
                bf16x8 a1 = *(const bf16x8*)(ap + kl * 8192 + 512);
                bf16x8 a2 = *(const bf16x8*)(ap + kl * 8192 + 1024);
                bf16x8 a3 = *(const bf16x8*)(ap + kl * 8192 + 1536);
                bf16x8 bb0 = *(const bf16x8*)(bp + kl * 64);
                bf16x8 bb1 = *(const bf16x8*)(bp + kl * 64 + 16 * 592);
                acc[0][0] = __builtin_amdgcn_mfma_f32_16x16x32_bf16(a0, bb0, acc[0][0], 0, 0, 0);
                acc[1][0] = __builtin_amdgcn_mfma_f32_16x16x32_bf16(a1, bb0, acc[1][0], 0, 0, 0);
                acc[2][0] = __builtin_amdgcn_mfma_f32_16x16x32_bf16(a2, bb0, acc[2][0], 0, 0, 0);
                acc[3][0] = __builtin_amdgcn_mfma_f32_16x16x32_bf16(a3, bb0, acc[3][0], 0, 0, 0);
                acc[0][1] = __builtin_amdgcn_mfma_f32_16x16x32_bf16(a0, bb1, acc[0][1], 0, 0, 0);
                acc[1][1] = __builtin_amdgcn_mfma_f32_16x16x32_bf16(a1, bb1, acc[1][1], 0, 0, 0);
                acc[2][1] = __builtin_amdgcn_mfma_f32_16x16x32_bf16(a2, bb1, acc[2][1], 0, 0, 0);
                acc[3][1] = __builtin_amdgcn_mfma_f32_16x16x32_bf16(a3, bb1, acc[3][1], 0, 0, 0);
            }
        }
    }

    // ---- epilogue: direct store (each wave holds full-K sums) -------------
    #pragma unroll
    for (int i = 0; i < 4; ++i) {
        #pragma unroll
        for (int n = 0; n < 2; ++n) {
            #pragma unroll
            for (int e = 0; e < 4; ++e) {
                int m = tm0 * 16 + i * 16 + q * 4 + e;
                out[((size_t)b * COUT + m) * HW + h * 64 + wb + n * 16 + rr]
                    = acc[i][n][e] + bias[m];
            }
        }
    }
}

extern "C" void kernel_launch(void* const* d_in, const int* in_sizes, int n_in,
                              void* d_out, int out_size, void* d_ws, size_t ws_size,
                              hipStream_t stream) {
    const float* x      = (const float*)d_in[0];   // [4,256,64,64]
    const float* off    = (const float*)d_in[1];   // [4,18,64,64]
    const float* msk    = (const float*)d_in[2];   // [4,9,64,64]
    const float* weight = (const float*)d_in[3];   // [256,256,3,3]
    const float* bias   = (const float*)d_in[4];   // [256]
    float* out = (float*)d_out;                    // [4,256,64,64]

    __bf16* wp = (__bf16*)d_ws;                    // 589824 bf16 = 1.18 MB

    prep_weights<<<256, 256, 0, stream>>>(weight, wp);
    dcn_main<<<512, 256, 0, stream>>>(x, off, msk, wp, bias, out);
}

// Round 3
// 133.340 us; speedup vs baseline: 1.2941x; 1.2193x over previous
//
#include <hip/hip_runtime.h>

typedef __bf16 bf16x8 __attribute__((ext_vector_type(8)));
typedef float f32x4 __attribute__((ext_vector_type(4)));

#define HH 64
#define WW 64
#define HW 4096
#define COUT 256
#define NROWS 12      // staged input rows [rowbase, rowbase+11]
#define XS_OFF 37888  // Xs after Bs (64 px rows x 592 B)
#define SMEM_SZ 65536 // Bs 37888 | Xs 24576 (12 rows x 2 sg x 64 col x 16 B)

// lgkm-only barrier: staging DMA stays in flight across it.
__device__ __forceinline__ void bar_sync() {
    asm volatile("s_waitcnt lgkmcnt(0)" ::: "memory");
    __builtin_amdgcn_s_barrier();
    asm volatile("" ::: "memory");
}
// full barrier: drains this wave's global_load_lds DMA before the barrier.
__device__ __forceinline__ void bar_sync_vm() {
    asm volatile("s_waitcnt vmcnt(0) lgkmcnt(0)" ::: "memory");
    __builtin_amdgcn_s_barrier();
    asm volatile("" ::: "memory");
}

// ---------------------------------------------------------------------------
// Kernel 1: blend circle weights -> bf16, pre-fragmented MFMA A layout.
// ---------------------------------------------------------------------------
__global__ __launch_bounds__(256) void prep_weights(const float* __restrict__ weight,
                                                    __bf16* __restrict__ wp) {
    __shared__ float ws[2304];
    const int o = blockIdx.x;
    const int tid = threadIdx.x;
    const float4* src = (const float4*)(weight + (size_t)o * 2304);
    float4* dst = (float4*)ws;
    #pragma unroll
    for (int i = 0; i < 3; ++i) {
        int idx = i * 256 + tid;
        if (idx < 576) dst[idx] = src[idx];
    }
    __syncthreads();
    const float Af = 0.70710678118654752f;
    const float Bf = 1.0f - Af;
    const int tm = o >> 4, rr = o & 15;
    for (int fid = tid; fid < 288; fid += 256) {
        const int cgtap = fid >> 2, q = fid & 3;
        const int cg = cgtap / 9, tap = cgtap - 9 * cg;
        const int c0 = cg * 32 + q * 8;
        bf16x8 v;
        #pragma unroll
        for (int j = 0; j < 8; ++j) {
            const float* w = ws + (c0 + j) * 9;
            float r;
            switch (tap) {
                case 0:  r = Af*(Af*w[0]+Bf*w[1]) + Bf*(Af*w[3]+Bf*w[4]); break;
                case 1:  r = w[1]; break;
                case 2:  r = Af*(Bf*w[1]+Af*w[2]) + Bf*(Bf*w[4]+Af*w[5]); break;
                case 3:  r = w[3]; break;
                case 4:  r = w[4]; break;
                case 5:  r = w[5]; break;
                case 6:  r = Bf*(Af*w[3]+Bf*w[4]) + Af*(Af*w[6]+Bf*w[7]); break;
                case 7:  r = w[7]; break;
                default: r = Bf*(Bf*w[4]+Af*w[5]) + Af*(Bf*w[7]+Af*w[8]); break;
            }
            v[j] = (__bf16)r;
        }
        *(bf16x8*)&wp[(size_t)(((cg * 9 + tap) * 16 + tm) * 64 + q * 16 + rr) << 3] = v;
    }
}

// ---------------------------------------------------------------------------
// Kernel 1b: transpose x -> bf16 stage-major layout for DMA staging.
// x[b][c][h][w] f32  ->  xs[b][h][g16][sg2][w64][c8] bf16  (8 MB)
// One block per (b,h). Coalesced reads; LDS [w][c ^ (w&31)] transpose
// (XOR keeps both ds_write and ds_read 2-way/conflict-free); coalesced
// 16 B/lane stores. Same bf16 rounding point as R0's in-kernel staging.
// ---------------------------------------------------------------------------
__global__ __launch_bounds__(256) void prep_x(const float* __restrict__ x,
                                              __bf16* __restrict__ xs) {
    __shared__ float lds[16384];   // [w64][c256], c XOR-swizzled by (w&31)
    const int bh = blockIdx.x;     // b*64 + h
    const int tid = threadIdx.x;
    const int b = bh >> 6, h = bh & 63;
    const int w4 = (tid & 15) * 4;
    const int cb = tid >> 4;       // 0..15
    #pragma unroll
    for (int it = 0; it < 16; ++it) {
        const int c = cb + it * 16;
        float4 v = *(const float4*)(x + ((size_t)(b * 256 + c)) * HW + h * 64 + w4);
        #pragma unroll
        for (int e = 0; e < 4; ++e) {
            int w = w4 + e;
            lds[w * 256 + (c ^ (w & 31))] = ((const float*)&v)[e];
        }
    }
    __syncthreads();
    #pragma unroll
    for (int it = 0; it < 8; ++it) {
        const int u = it * 256 + tid;        // 16B chunk index 0..2047
        const int gsg = u >> 6, w = u & 63;  // c = gsg*8 + c8
        bf16x8 v;
        #pragma unroll
        for (int c8 = 0; c8 < 8; ++c8)
            v[c8] = (__bf16)lds[w * 256 + ((gsg * 8 + c8) ^ (w & 31))];
        *(bf16x8*)&xs[(size_t)bh * 16384 + (size_t)u * 8] = v;
    }
}

// ---------------------------------------------------------------------------
// Kernel 2: DMA-staged bilinear-sample + implicit GEMM. R0's proven skeleton
// (256 blocks x 512 thr, 1 block/CU, kl-split MFMA with prefetch, LDS reduce
// epilogue) with the staging phase replaced by 3 global_load_lds(width=16)
// per wave per stage from the pre-transposed xs: zero staging VALU, zero
// staging VGPRs, one fewer barrier per stage. Xs layout row*2048+sg*1024+
// col*16 -> gather b128 reads at 16 B lane stride (conflict-free), full-width
// col window (no col fallback; row fallback as R0).
// ---------------------------------------------------------------------------
__global__ __launch_bounds__(512, 2) void dcn_main(
        const float* __restrict__ x, const float* __restrict__ off,
        const float* __restrict__ msk, const __bf16* __restrict__ wp,
        const __bf16* __restrict__ xs, const float* __restrict__ bias,
        float* __restrict__ out) {
    __shared__ __align__(16) char smem[SMEM_SZ];  // Bs | Xs; epilogue: f32 scratch
    char* BsB = smem;
    const char* XsB = (const char*)smem + XS_OFF;

    const int tid  = threadIdx.x;
    const int wv   = tid >> 6;
    const int lane = tid & 63;
    const int q    = lane >> 4, rr = lane & 15;
    const int px   = lane;                 // sampling pixel column

    const int bid = blockIdx.x;
    const int xcd = bid & 7;
    const int b   = xcd >> 1;
    const int h   = ((xcd & 1) << 5) | (bid >> 3);

    const int rowbase = min(max(h - 5, 0), HH - NROWS);
    const float* xb = x + (size_t)b * 256 * HW;
    const char* xsb = (const char*)xs;

    // ---- DMA strip assignment: 24 strips (12 rows x 2 sg), 3 per wave -----
    // strip t: row = t>>1, sg = t&1. src 1024 B contiguous; dest linear.
    size_t SB[3]; int XD[3];
    #pragma unroll
    for (int k = 0; k < 3; ++k) {
        int t = wv * 3 + k;
        int row = t >> 1, sgh = t & 1;
        SB[k] = (size_t)(b * 64 + rowbase + row) * 32768 + (size_t)(sgh * 1024 + lane * 16);
        XD[k] = XS_OFF + row * 2048 + sgh * 1024;
    }

    // ---- per-thread gather-unit params, computed ONCE ---------------------
    // unit c (0..17): k=0 -> c=wv; k=1 -> c=wv+8; k=2 -> c=wv+10 (waves 6,7).
    float W00[3], W01[3], W10[3], W11[3];
    int AY0[3], AY1[3], DXO[3], COLB[3], GP[3];
    bool UV[3];
    #pragma unroll
    for (int k = 0; k < 3; ++k) {
        int c = (k < 2) ? (wv + 8 * k) : ((wv >= 6) ? wv + 10 : -1);
        UV[k] = (c >= 0);
        if (UV[k]) {
            int sg = c / 9, tap = c % 9;
            int ki = tap / 3, kj = tap - 3 * ki;
            const float* offp = off + (size_t)b * 18 * HW + h * 64 + px;
            float dy = offp[(2 * tap) * HW];
            float dx = offp[(2 * tap + 1) * HW];
            float mv = msk[(size_t)b * 9 * HW + (size_t)tap * HW + h * 64 + px];
            float py  = (float)(h - 1 + ki) + dy;
            float pxf = (float)(px - 1 + kj) + dx;
            float y0f = floorf(py), x0f = floorf(pxf);
            float ly = py - y0f, lx = pxf - x0f;
            float hy = 1.0f - ly, hx = 1.0f - lx;
            int y0 = (int)y0f, x0 = (int)x0f;
            int y1 = y0 + 1, x1 = x0 + 1;
            bool vy0 = (y0 >= 0) && (y0 < HH), vy1 = (y1 >= 0) && (y1 < HH);
            bool vx0 = (x0 >= 0) && (x0 < WW), vx1 = (x1 >= 0) && (x1 < WW);
            int cy0 = min(max(y0, 0), HH - 1), cy1 = min(max(y1, 0), HH - 1);
            int cx0 = min(max(x0, 0), WW - 1), cx1 = min(max(x1, 0), WW - 1);
            W00[k] = (vy0 && vx0) ? hy * hx * mv : 0.0f;
            W01[k] = (vy0 && vx1) ? hy * lx * mv : 0.0f;
            W10[k] = (vy1 && vx0) ? ly * hx * mv : 0.0f;
            W11[k] = (vy1 && vx1) ? ly * lx * mv : 0.0f;
            int ry0 = min(max(cy0 - rowbase, 0), NROWS - 1);
            int ry1 = min(max(cy1 - rowbase, 0), NROWS - 1);
            bool useG = (vy0 && (cy0 < rowbase || cy0 > rowbase + NROWS - 1))
                     || (vy1 && (cy1 < rowbase || cy1 > rowbase + NROWS - 1));
            AY0[k]  = ry0 * 2048 + sg * 1024 + cx0 * 16;
            AY1[k]  = ry1 * 2048 + sg * 1024 + cx0 * 16;
            DXO[k]  = (cx1 - cx0) * 16;
            COLB[k] = (tap * 32 + sg * 8) * 2;
            GP[k]   = cy0 | (cy1 << 6) | (cx0 << 12) | (cx1 << 18) | (sg << 24)
                    | (useG ? (1u << 31) : 0);
        }
    }

    f32x4 acc[4][4];
    #pragma unroll
    for (int i = 0; i < 4; ++i)
        #pragma unroll
        for (int n = 0; n < 4; ++n)
            acc[i][n] = (f32x4)0.0f;

    const int tm0   = (wv & 3) * 4;
    const int klbeg = (wv & 4) ? 5 : 0;
    const int nkl   = (wv & 4) ? 4 : 5;

    // ---- prologue: DMA stage 0 --------------------------------------------
    #pragma unroll
    for (int k = 0; k < 3; ++k)
        __builtin_amdgcn_global_load_lds(
            (const __attribute__((address_space(1))) void*)(xsb + SB[k]),
            (__attribute__((address_space(3))) void*)(smem + XD[k]), 16, 0, 0);

    #pragma unroll 1
    for (int s = 0; s < 16; ++s) {
        const int cg = s >> 1, half = s & 1;
        bar_sync_vm();   // Xs(s) landed block-wide; Bs(cg-1) MFMA reads done
        // ---- gather: <=3 (c,px) units per thread --------------------------
        #pragma unroll
        for (int k = 0; k < 3; ++k) {
            if (UV[k]) {
                bf16x8 c00 = *(const bf16x8*)(XsB + AY0[k]);
                bf16x8 c01 = *(const bf16x8*)(XsB + AY0[k] + DXO[k]);
                bf16x8 c10 = *(const bf16x8*)(XsB + AY1[k]);
                bf16x8 c11 = *(const bf16x8*)(XsB + AY1[k] + DXO[k]);
                float w0 = W00[k], w1 = W01[k], w2 = W10[k], w3 = W11[k];
                bf16x8 res;
                #pragma unroll
                for (int j = 0; j < 8; ++j) {
                    float v = w0 * (float)c00[j] + w1 * (float)c01[j]
                            + w2 * (float)c10[j] + w3 * (float)c11[j];
                    res[j] = (__bf16)v;
                }
                int gp = GP[k];
                if (gp < 0) {   // rare: valid corner outside staged rows
                    int cy0 = gp & 63, cy1 = (gp >> 6) & 63;
                    int cx0 = (gp >> 12) & 63, cx1 = (gp >> 18) & 63;
                    int sg = (gp >> 24) & 3;
                    const float* xc = xb + (size_t)(cg * 32 + half * 16 + sg * 8) * HW;
                    int i00 = cy0 * 64 + cx0, i01 = cy0 * 64 + cx1;
                    int i10 = cy1 * 64 + cx0, i11 = cy1 * 64 + cx1;
                    #pragma unroll
                    for (int j = 0; j < 8; ++j) {
                        float v = w0 * xc[i00] + w1 * xc[i01]
                                + w2 * xc[i10] + w3 * xc[i11];
                        res[j] = (__bf16)v;
                        xc += HW;
                    }
                }
                *(bf16x8*)(BsB + px * 592 + COLB[k] + half * 32) = res;
            }
        }
        bar_sync();   // Xs reads + Bs(half) writes done block-wide
        // ---- issue next stage's DMA (flies across MFMA + next barrier) ----
        if (s < 15) {
            #pragma unroll
            for (int k = 0; k < 3; ++k)
                __builtin_amdgcn_global_load_lds(
                    (const __attribute__((address_space(1))) void*)(xsb + SB[k] + (size_t)(s + 1) * 2048),
                    (__attribute__((address_space(3))) void*)(smem + XD[k]), 16, 0, 0);
        }
        if (half) {
            // ---- MFMA: M=64/wave, 4 n-tiles, kl split across wave halves --
            const __bf16* ap = wp + ((size_t)((cg * 9 + klbeg) * 16 + tm0) * 64 + lane) * 8;
            bf16x8 a0 = *(const bf16x8*)ap;
            bf16x8 a1 = *(const bf16x8*)(ap + 512);
            bf16x8 a2 = *(const bf16x8*)(ap + 1024);
            bf16x8 a3 = *(const bf16x8*)(ap + 1536);
            int kc = (klbeg * 32 + q * 8) * 2;   // byte col in Bs row
            #pragma unroll 1
            for (int t = 0; t < nkl; ++t) {
                bf16x8 n0 = a0, n1 = a1, n2 = a2, n3 = a3;
                if (t + 1 < nkl) {
                    const __bf16* np = ap + 8192;
                    n0 = *(const bf16x8*)np;
                    n1 = *(const bf16x8*)(np + 512);
                    n2 = *(const bf16x8*)(np + 1024);
                    n3 = *(const bf16x8*)(np + 1536);
                }
                const char* bp = BsB + rr * 592 + kc;
                bf16x8 bb0 = *(const bf16x8*)(bp);
                bf16x8 bb1 = *(const bf16x8*)(bp + 16 * 592);
                bf16x8 bb2 = *(const bf16x8*)(bp + 32 * 592);
                bf16x8 bb3 = *(const bf16x8*)(bp + 48 * 592);
                acc[0][0] = __builtin_amdgcn_mfma_f32_16x16x32_bf16(a0, bb0, acc[0][0], 0, 0, 0);
                acc[1][0] = __builtin_amdgcn_mfma_f32_16x16x32_bf16(a1, bb0, acc[1][0], 0, 0, 0);
                acc[2][0] = __builtin_amdgcn_mfma_f32_16x16x32_bf16(a2, bb0, acc[2][0], 0, 0, 0);
                acc[3][0] = __builtin_amdgcn_mfma_f32_16x16x32_bf16(a3, bb0, acc[3][0], 0, 0, 0);
                acc[0][1] = __builtin_amdgcn_mfma_f32_16x16x32_bf16(a0, bb1, acc[0][1], 0, 0, 0);
                acc[1][1] = __builtin_amdgcn_mfma_f32_16x16x32_bf16(a1, bb1, acc[1][1], 0, 0, 0);
                acc[2][1] = __builtin_amdgcn_mfma_f32_16x16x32_bf16(a2, bb1, acc[2][1], 0, 0, 0);
                acc[3][1] = __builtin_amdgcn_mfma_f32_16x16x32_bf16(a3, bb1, acc[3][1], 0, 0, 0);
                acc[0][2] = __builtin_amdgcn_mfma_f32_16x16x32_bf16(a0, bb2, acc[0][2], 0, 0, 0);
                acc[1][2] = __builtin_amdgcn_mfma_f32_16x16x32_bf16(a1, bb2, acc[1][2], 0, 0, 0);
                acc[2][2] = __builtin_amdgcn_mfma_f32_16x16x32_bf16(a2, bb2, acc[2][2], 0, 0, 0);
                acc[3][2] = __builtin_amdgcn_mfma_f32_16x16x32_bf16(a3, bb2, acc[3][2], 0, 0, 0);
                acc[0][3] = __builtin_amdgcn_mfma_f32_16x16x32_bf16(a0, bb3, acc[0][3], 0, 0, 0);
                acc[1][3] = __builtin_amdgcn_mfma_f32_16x16x32_bf16(a1, bb3, acc[1][3], 0, 0, 0);
                acc[2][3] = __builtin_amdgcn_mfma_f32_16x16x32_bf16(a2, bb3, acc[2][3], 0, 0, 0);
                acc[3][3] = __builtin_amdgcn_mfma_f32_16x16x32_bf16(a3, bb3, acc[3][3], 0, 0, 0);
                ap += 8192;
                kc += 64;
                a0 = n0; a1 = n1; a2 = n2; a3 = n3;
            }
        }
    }

    // ---- epilogue: cross-wave kl-partial reduce via LDS, then store -------
    float* scr = (float*)smem;   // Bs/Xs dead now
    bar_sync();
    if (wv >= 4) {
        const int base = (wv - 4) * 4096 + lane * 4;
        #pragma unroll
        for (int i = 0; i < 4; ++i)
            #pragma unroll
            for (int n = 0; n < 4; ++n)
                *(f32x4*)&scr[base + (i * 4 + n) * 256] = acc[i][n];
    }
    bar_sync();
    if (wv < 4) {
        const int mrow = wv * 64;
        const int base = wv * 4096 + lane * 4;
        #pragma unroll
        for (int i = 0; i < 4; ++i) {
            #pragma unroll
            for (int n = 0; n < 4; ++n) {
                f32x4 p = *(const f32x4*)&scr[base + (i * 4 + n) * 256];
                #pragma unroll
                for (int e = 0; e < 4; ++e) {
                    int m = mrow + i * 16 + q * 4 + e;
                    out[((size_t)b * COUT + m) * HW + h * 64 + n * 16 + rr]
                        = acc[i][n][e] + p[e] + bias[m];
                }
            }
        }
    }
}

extern "C" void kernel_launch(void* const* d_in, const int* in_sizes, int n_in,
                              void* d_out, int out_size, void* d_ws, size_t ws_size,
                              hipStream_t stream) {
    const float* x      = (const float*)d_in[0];   // [4,256,64,64]
    const float* off    = (const float*)d_in[1];   // [4,18,64,64]
    const float* msk    = (const float*)d_in[2];   // [4,9,64,64]
    const float* weight = (const float*)d_in[3];   // [256,256,3,3]
    const float* bias   = (const float*)d_in[4];   // [256]
    float* out = (float*)d_out;                    // [4,256,64,64]

    __bf16* wp = (__bf16*)d_ws;                              // 1.18 MB
    __bf16* xs = (__bf16*)((char*)d_ws + 1179648);           // 8 MB transposed x

    prep_weights<<<256, 256, 0, stream>>>(weight, wp);
    prep_x<<<256, 256, 0, stream>>>(x, xs);
    dcn_main<<<256, 512, 0, stream>>>(x, off, msk, wp, xs, bias, out);
}